// Round 1
// baseline (986.514 us; speedup 1.0000x reference)
//
#include <hip/hip_runtime.h>
#include <math.h>

#define B_ 32
#define C_ 256
#define N_ 4096
#define HID_ 128
#define OC3_ 384
#define HEADS_ 4
#define DH_ 32
#define LNM_ (C_*N_)

// ---------------- K0: zero scratch (ctx + rmax + rinv + bsum) ----------------
__global__ void k_zero(float* __restrict__ p, int n) {
  int i = blockIdx.x * blockDim.x + threadIdx.x;
  int stride = gridDim.x * blockDim.x;
  for (; i < n; i += stride) p[i] = 0.f;
}

// ---------------- K1/K4: tiled fp32 GEMM ----------------
// C[b][m][n] = sum_k A[m][k] * X[b][k][n]   (row strides of X,C are N_)
// BM=BN=64, BK=16, 256 threads, 4x4 per thread.
// If bias != nullptr: add bias[m] and accumulate LayerNorm partial sums into bsum[2b],bsum[2b+1].
__global__ __launch_bounds__(256) void k_gemm(
    const float* __restrict__ A, const float* __restrict__ Xall,
    float* __restrict__ Call, int K, long strideX, long strideC,
    const float* __restrict__ bias, float* __restrict__ bsum) {
  int b = blockIdx.z;
  const float* X = Xall + (size_t)b * strideX;
  float* Co = Call + (size_t)b * strideC;
  int m0 = blockIdx.y * 64, n0 = blockIdx.x * 64;
  __shared__ float As[16][68];   // [kk][m], pad 68 keeps float4 reads 16B-aligned, <=2-way banks
  __shared__ float Bs[16][68];   // [kk][n]
  int tid = threadIdx.x;
  int tx = tid & 15, ty = tid >> 4;
  float acc[4][4] = {};
  for (int k0 = 0; k0 < K; k0 += 16) {
    {
      int kk = tid & 15, mb = tid >> 4;
      #pragma unroll
      for (int i = 0; i < 4; i++)
        As[kk][mb + 16*i] = A[(m0 + mb + 16*i) * K + k0 + kk];
    }
    {
      int nn = tid & 63, kr = tid >> 6;
      #pragma unroll
      for (int i = 0; i < 4; i++)
        Bs[kr + 4*i][nn] = X[(size_t)(k0 + kr + 4*i) * N_ + n0 + nn];
    }
    __syncthreads();
    #pragma unroll
    for (int kk = 0; kk < 16; kk++) {
      float4 a4 = *(const float4*)&As[kk][ty * 4];
      float4 b4 = *(const float4*)&Bs[kk][tx * 4];
      float aa[4] = {a4.x, a4.y, a4.z, a4.w};
      float bb[4] = {b4.x, b4.y, b4.z, b4.w};
      #pragma unroll
      for (int i = 0; i < 4; i++)
        #pragma unroll
        for (int j = 0; j < 4; j++)
          acc[i][j] += aa[i] * bb[j];
    }
    __syncthreads();
  }
  float s1 = 0.f, s2 = 0.f;
  #pragma unroll
  for (int i = 0; i < 4; i++) {
    int m = m0 + ty * 4 + i;
    float bv = bias ? bias[m] : 0.f;
    float4 r;
    r.x = acc[i][0] + bv; r.y = acc[i][1] + bv;
    r.z = acc[i][2] + bv; r.w = acc[i][3] + bv;
    if (bias) {
      s1 += r.x + r.y + r.z + r.w;
      s2 += r.x*r.x + r.y*r.y + r.z*r.z + r.w*r.w;
    }
    *(float4*)&Co[(size_t)m * N_ + n0 + tx * 4] = r;
  }
  if (bias) {
    __shared__ float red[8];
    #pragma unroll
    for (int o = 32; o; o >>= 1) { s1 += __shfl_xor(s1, o); s2 += __shfl_xor(s2, o); }
    int w = tid >> 6;
    if ((tid & 63) == 0) { red[w] = s1; red[4 + w] = s2; }
    __syncthreads();
    if (tid == 0) {
      float t1 = red[0] + red[1] + red[2] + red[3];
      float t2 = red[4] + red[5] + red[6] + red[7];
      atomicAdd(&bsum[2*b], t1);
      atomicAdd(&bsum[2*b+1], t2);
    }
  }
}

// ---------------- K2a: per-row max and 1/sum(exp) for k-softmax over n ----------------
__global__ __launch_bounds__(256) void k_kstats(const float* __restrict__ qkv,
    float* __restrict__ rmax, float* __restrict__ rinv) {
  int r = blockIdx.x;              // 0..4095 = (b*HEADS + hd)*32 + d
  int b = r >> 7, rem = r & 127;   // rem = hd*32 + d
  const float* row = qkv + (size_t)b * OC3_ * N_ + (size_t)(HID_ + rem) * N_;
  int tid = threadIdx.x;
  float m = -1e30f;
  for (int n = tid; n < N_; n += 256) m = fmaxf(m, row[n]);
  #pragma unroll
  for (int o = 32; o; o >>= 1) m = fmaxf(m, __shfl_xor(m, o));
  __shared__ float sm[4], ss[4];
  int w = tid >> 6;
  if ((tid & 63) == 0) sm[w] = m;
  __syncthreads();
  m = fmaxf(fmaxf(sm[0], sm[1]), fmaxf(sm[2], sm[3]));
  float s = 0.f;
  for (int n = tid; n < N_; n += 256) s += __expf(row[n] - m);
  #pragma unroll
  for (int o = 32; o; o >>= 1) s += __shfl_xor(s, o);
  if ((tid & 63) == 0) ss[w] = s;
  __syncthreads();
  if (tid == 0) {
    s = ss[0] + ss[1] + ss[2] + ss[3];
    rmax[r] = m;
    rinv[r] = 1.f / s;
  }
}

// ---------------- K2b: context[d][e] = sum_n softmax(k)[d][n] * v[e][n] ----------------
// grid (32 chunks of 128 n, 128 bh); atomic accumulate into ctx
#define CH_ 128
__global__ __launch_bounds__(256) void k_context(const float* __restrict__ qkv,
    const float* __restrict__ rmax, const float* __restrict__ rinv,
    float* __restrict__ ctx) {
  int chunk = blockIdx.x;
  int bh = blockIdx.y;
  int b = bh >> 2, hd = bh & 3;
  const float* kbase = qkv + (size_t)b*OC3_*N_ + (size_t)(HID_ + hd*DH_)*N_ + chunk*CH_;
  const float* vbase = qkv + (size_t)b*OC3_*N_ + (size_t)(2*HID_ + hd*DH_)*N_ + chunk*CH_;
  __shared__ float ks[32][CH_ + 1];  // stride 129 -> bank (d+n)%32, conflict-free d-reads
  __shared__ float vs[CH_][36];      // transposed, row 144B (16B-aligned float4)
  int tid = threadIdx.x;
  for (int idx = tid; idx < 32 * CH_; idx += 256) {
    int d = idx >> 7, n = idx & (CH_ - 1);
    int r = bh * 32 + d;
    ks[d][n] = __expf(kbase[(size_t)d * N_ + n] - rmax[r]) * rinv[r];
    vs[n][d] = vbase[(size_t)d * N_ + n];
  }
  __syncthreads();
  int d = tid >> 3, e0 = (tid & 7) << 2;
  float4 acc = {0.f, 0.f, 0.f, 0.f};
  for (int n = 0; n < CH_; n++) {
    float kd = ks[d][n];
    float4 v4 = *(const float4*)&vs[n][e0];
    acc.x += kd * v4.x; acc.y += kd * v4.y;
    acc.z += kd * v4.z; acc.w += kd * v4.w;
  }
  float* cp = &ctx[(size_t)(bh * 32 + d) * 32 + e0];
  atomicAdd(cp + 0, acc.x); atomicAdd(cp + 1, acc.y);
  atomicAdd(cp + 2, acc.z); atomicAdd(cp + 3, acc.w);
}

// ---------------- K3: q-softmax over d + hid[e][n] = sum_d ctx[d][e]*qs[d][n] ----------------
// writes hid into the (dead) v-slice of qkv
__global__ __launch_bounds__(256) void k_attnout(float* __restrict__ qkv,
    const float* __restrict__ ctx) {
  int tile = blockIdx.x;   // 0..15, 256 cols each
  int bh = blockIdx.y;     // 0..127
  int b = bh >> 2, hd = bh & 3;
  const float* qbase = qkv + (size_t)b*OC3_*N_ + (size_t)(hd*DH_)*N_;
  float* obase = qkv + (size_t)b*OC3_*N_ + (size_t)(2*HID_ + hd*DH_)*N_;
  __shared__ float cs[32][36];
  int tid = threadIdx.x;
  for (int idx = tid; idx < 1024; idx += 256) {
    int d = idx >> 5, e = idx & 31;
    cs[d][e] = ctx[(size_t)bh * 1024 + idx];
  }
  __syncthreads();
  int n = tile * 256 + tid;
  float q[32];
  float m = -1e30f;
  #pragma unroll
  for (int d = 0; d < 32; d++) { q[d] = qbase[(size_t)d * N_ + n]; m = fmaxf(m, q[d]); }
  float s = 0.f;
  #pragma unroll
  for (int d = 0; d < 32; d++) { q[d] = __expf(q[d] - m); s += q[d]; }
  float inv = 0.17677669529663687f / s;  // scale = 1/sqrt(32)
  #pragma unroll
  for (int d = 0; d < 32; d++) q[d] *= inv;
  #pragma unroll
  for (int e0 = 0; e0 < 32; e0 += 4) {
    float4 a = {0.f, 0.f, 0.f, 0.f};
    #pragma unroll
    for (int d = 0; d < 32; d++) {
      float4 c4 = *(const float4*)&cs[d][e0];
      a.x += c4.x * q[d]; a.y += c4.y * q[d];
      a.z += c4.z * q[d]; a.w += c4.w * q[d];
    }
    obase[(size_t)(e0 + 0) * N_ + n] = a.x;
    obase[(size_t)(e0 + 1) * N_ + n] = a.y;
    obase[(size_t)(e0 + 2) * N_ + n] = a.z;
    obase[(size_t)(e0 + 3) * N_ + n] = a.w;
  }
}

// ---------------- K5: finalize mean/rstd per batch ----------------
__global__ void k_finalize(float* __restrict__ bsum) {
  int b = threadIdx.x;
  if (b < B_) {
    float s1 = bsum[2*b], s2 = bsum[2*b+1];
    float mean = s1 * (1.f / LNM_);
    float var = s2 * (1.f / LNM_) - mean * mean;
    float rstd = rsqrtf(var + 1e-5f);
    bsum[2*b] = mean;
    bsum[2*b+1] = rstd;
  }
}

// ---------------- K6: in-place normalize + affine ----------------
__global__ __launch_bounds__(256) void k_norm(float* __restrict__ out,
    const float* __restrict__ bsum, const float* __restrict__ gnw,
    const float* __restrict__ gnb) {
  size_t v = (size_t)blockIdx.x * 256 + threadIdx.x;  // float4 index
  int c = (int)((v >> 10) & 255);
  int b = (int)(v >> 18);
  float mean = bsum[2*b], rstd = bsum[2*b+1];
  float w = gnw[c] * rstd;
  float sh = gnb[c] - mean * w;
  float4 x = ((const float4*)out)[v];
  x.x = x.x * w + sh; x.y = x.y * w + sh;
  x.z = x.z * w + sh; x.w = x.w * w + sh;
  ((float4*)out)[v] = x;
}

extern "C" void kernel_launch(void* const* d_in, const int* in_sizes, int n_in,
                              void* d_out, int out_size, void* d_ws, size_t ws_size,
                              hipStream_t stream) {
  const float* x     = (const float*)d_in[0];
  const float* w_qkv = (const float*)d_in[1];
  const float* w_out = (const float*)d_in[2];
  const float* b_out = (const float*)d_in[3];
  const float* gn_w  = (const float*)d_in[4];
  const float* gn_b  = (const float*)d_in[5];
  float* out = (float*)d_out;
  float* ws  = (float*)d_ws;

  float* qkv  = ws;                                   // B*384*N
  float* ctx  = qkv + (size_t)B_ * OC3_ * N_;         // B*HEADS*32*32 = 131072
  float* rmax = ctx + (size_t)B_ * HEADS_ * DH_ * DH_;// 4096
  float* rinv = rmax + 4096;                          // 4096
  float* bsum = rinv + 4096;                          // 64

  // zero ctx..bsum (atomically accumulated)
  k_zero<<<64, 256, 0, stream>>>(ctx, 131072 + 4096 + 4096 + 64);
  // qkv = w_qkv @ x  per batch
  k_gemm<<<dim3(64, 6, 32), 256, 0, stream>>>(w_qkv, x, qkv, 256,
      (long)C_ * N_, (long)OC3_ * N_, nullptr, nullptr);
  // k softmax stats
  k_kstats<<<4096, 256, 0, stream>>>(qkv, rmax, rinv);
  // context
  k_context<<<dim3(N_ / CH_, B_ * HEADS_), 256, 0, stream>>>(qkv, rmax, rinv, ctx);
  // attention out -> v-slice of qkv
  k_attnout<<<dim3(16, B_ * HEADS_), 256, 0, stream>>>(qkv, ctx);
  // projection + bias + LN partials -> d_out
  k_gemm<<<dim3(64, 4, 32), 256, 0, stream>>>(w_out, qkv + (size_t)2 * HID_ * N_, out, 128,
      (long)OC3_ * N_, (long)C_ * N_, b_out, bsum);
  // finalize LN stats
  k_finalize<<<1, 64, 0, stream>>>(bsum);
  // normalize in-place
  k_norm<<<(B_ * C_ * N_) / 4 / 256, 256, 0, stream>>>(out, bsum, gn_w, gn_b);
}

// Round 2
// 486.678 us; speedup vs baseline: 2.0270x; 2.0270x over previous
//
#include <hip/hip_runtime.h>
#include <math.h>

#define B_ 32
#define C_ 256
#define N_ 4096
#define HID_ 128
#define OC3_ 384
#define HEADS_ 4
#define DH_ 32
#define LNM_ (C_*N_)

typedef unsigned short u16;
typedef __attribute__((ext_vector_type(8))) short short8;
typedef __attribute__((ext_vector_type(4))) float f32x4;

__device__ inline u16 f2b(float f) {
  union { float f; unsigned int u; } c; c.f = f;
  unsigned int u = c.u;
  return (u16)((u + 0x7fffu + ((u >> 16) & 1u)) >> 16);  // RNE
}
__device__ inline float b2f(u16 b) {
  union { float f; unsigned int u; } c; c.u = (unsigned int)b << 16; return c.f;
}
__device__ inline void load_lds16(const u16* g, u16* l) {
  __builtin_amdgcn_global_load_lds(
      (const __attribute__((address_space(1))) void*)g,
      (__attribute__((address_space(3))) void*)l, 16, 0, 0);
}

// ---------------- K-1: cast weights to bf16 ----------------
__global__ void k_cast_w(const float* __restrict__ wq, const float* __restrict__ wo,
                         u16* __restrict__ wqb, u16* __restrict__ wob) {
  int i = blockIdx.x * 256 + threadIdx.x;
  if (i < OC3_ * C_) wqb[i] = f2b(wq[i]);
  if (i < C_ * HID_) wob[i] = f2b(wo[i]);
}

// ---------------- K0: transpose+cast x[b][c][n] -> xt[b][n][c] bf16 ----------------
__global__ __launch_bounds__(256) void k_transpose(const float* __restrict__ x,
                                                   u16* __restrict__ xt) {
  int b = blockIdx.z;
  int n0 = blockIdx.x * 64, c0 = blockIdx.y * 64;
  __shared__ float t[64][65];
  const float* xp = x + (size_t)b * C_ * N_;
  u16* xo = xt + (size_t)b * N_ * C_;
  int tid = threadIdx.x;
  int r = tid >> 4, c4 = (tid & 15) * 4;
  #pragma unroll
  for (int i = 0; i < 4; i++) {
    int cl = r + i * 16;
    float4 v = *(const float4*)&xp[(size_t)(c0 + cl) * N_ + n0 + c4];
    t[cl][c4 + 0] = v.x; t[cl][c4 + 1] = v.y; t[cl][c4 + 2] = v.z; t[cl][c4 + 3] = v.w;
  }
  __syncthreads();
  #pragma unroll
  for (int i = 0; i < 4; i++) {
    int nl = r + i * 16;
    ushort4 o;
    o.x = f2b(t[c4 + 0][nl]); o.y = f2b(t[c4 + 1][nl]);
    o.z = f2b(t[c4 + 2][nl]); o.w = f2b(t[c4 + 3][nl]);
    *(ushort4*)&xo[(size_t)(n0 + nl) * C_ + c0 + c4] = o;
  }
}

// ---------------- K0b: zero ctx + bsum ----------------
__global__ void k_zero(float* __restrict__ p, int n) {
  int i = blockIdx.x * blockDim.x + threadIdx.x;
  int stride = gridDim.x * blockDim.x;
  for (; i < n; i += stride) p[i] = 0.f;
}

// ---------------- bf16 MFMA GEMM:  C[b][m][n] = sum_k A[m][k] * Bt[b][n][k] ----------------
// 128x128 tile, BK=32, 4 waves (2x2 of 64x64), global_load_lds staging.
// LDS layout per tile: [k-chunk c(0..3)][row(0..127)] of 8 bf16 (16B) — frag reads are
// 16 contiguous 16B chunks per quad (2-way bank alias = free).
template<int KDIM, bool OUTBF16>
__global__ __launch_bounds__(256) void k_gemm_mfma(
    const u16* __restrict__ A, const u16* __restrict__ Ball, void* __restrict__ Call,
    const float* __restrict__ bias, float* __restrict__ bsum, int Mtot) {
  int b = blockIdx.z;
  int m0 = blockIdx.y * 128, n0 = blockIdx.x * 128;
  const u16* Bt = Ball + (size_t)b * N_ * KDIM;
  __shared__ __align__(16) u16 As[4096];  // 4 chunks * 128 rows * 8 bf16 = 8 KiB
  __shared__ __align__(16) u16 Bs[4096];
  __shared__ float red[8];
  int tid = threadIdx.x;
  int w = tid >> 6, l = tid & 63, l16 = l & 15, quad = l >> 4;
  int wm = w & 1, wn = w >> 1;
  f32x4 acc[4][4] = {};

  for (int k0 = 0; k0 < KDIM; k0 += 32) {
    #pragma unroll
    for (int i = 0; i < 2; i++) {
      int chunk = i * 256 + tid;
      int c = chunk >> 7, m = chunk & 127;
      const u16* ga = A  + (size_t)(m0 + m) * KDIM + k0 + c * 8;
      const u16* gb = Bt + (size_t)(n0 + m) * KDIM + k0 + c * 8;
      u16* la = As + (size_t)(i * 256 + (tid & ~63)) * 8;
      u16* lb = Bs + (size_t)(i * 256 + (tid & ~63)) * 8;
      load_lds16(ga, la);
      load_lds16(gb, lb);
    }
    __syncthreads();
    short8 af[4], bf[4];
    #pragma unroll
    for (int mi = 0; mi < 4; mi++)
      af[mi] = *(const short8*)&As[(size_t)(quad * 128 + wm * 64 + mi * 16 + l16) * 8];
    #pragma unroll
    for (int nj = 0; nj < 4; nj++)
      bf[nj] = *(const short8*)&Bs[(size_t)(quad * 128 + wn * 64 + nj * 16 + l16) * 8];
    #pragma unroll
    for (int mi = 0; mi < 4; mi++)
      #pragma unroll
      for (int nj = 0; nj < 4; nj++)
        acc[mi][nj] = __builtin_amdgcn_mfma_f32_16x16x32_bf16(af[mi], bf[nj], acc[mi][nj], 0, 0, 0);
    __syncthreads();
  }

  if constexpr (OUTBF16) {
    // LDS repack (wave-private 2 KiB region) -> coalesced 16B bf16 stores
    u16* Co = (u16*)Call + (size_t)b * Mtot * N_;
    u16* lw = As + w * 1024;  // 16 rows x 64 cols bf16
    #pragma unroll
    for (int mi = 0; mi < 4; mi++) {
      #pragma unroll
      for (int nj = 0; nj < 4; nj++)
        #pragma unroll
        for (int r = 0; r < 4; r++)
          lw[(quad * 4 + r) * 64 + nj * 16 + l16] = f2b(acc[mi][nj][r]);
      #pragma unroll
      for (int p = 0; p < 2; p++) {
        int chunk = p * 64 + l;           // 128 chunks of 8 bf16
        int row = chunk >> 3, cc = chunk & 7;
        uint4 v = *(const uint4*)&lw[chunk * 8];
        *(uint4*)&Co[(size_t)(m0 + wm * 64 + mi * 16 + row) * N_ + n0 + wn * 64 + cc * 8] = v;
      }
    }
  } else {
    // fp32 + bias + LayerNorm partial sums
    float* Co = (float*)Call + (size_t)b * Mtot * N_;
    float s1 = 0.f, s2 = 0.f;
    #pragma unroll
    for (int mi = 0; mi < 4; mi++)
      #pragma unroll
      for (int r = 0; r < 4; r++) {
        int m = m0 + wm * 64 + mi * 16 + quad * 4 + r;
        float bv = bias[m];
        #pragma unroll
        for (int nj = 0; nj < 4; nj++) {
          int n = n0 + wn * 64 + nj * 16 + l16;
          float v = acc[mi][nj][r] + bv;
          s1 += v; s2 += v * v;
          Co[(size_t)m * N_ + n] = v;
        }
      }
    #pragma unroll
    for (int o = 32; o; o >>= 1) { s1 += __shfl_xor(s1, o); s2 += __shfl_xor(s2, o); }
    if (l == 0) { red[w] = s1; red[4 + w] = s2; }
    __syncthreads();
    if (tid == 0) {
      atomicAdd(&bsum[2 * b],     red[0] + red[1] + red[2] + red[3]);
      atomicAdd(&bsum[2 * b + 1], red[4] + red[5] + red[6] + red[7]);
    }
  }
}

// ---------------- K2a: k-softmax stats over n ----------------
__global__ __launch_bounds__(256) void k_kstats(const u16* __restrict__ qkvb,
    float* __restrict__ rmax, float* __restrict__ rinv) {
  int r = blockIdx.x;
  int b = r >> 7, rem = r & 127;
  const u16* row = qkvb + (size_t)b * OC3_ * N_ + (size_t)(HID_ + rem) * N_;
  int tid = threadIdx.x;
  float v[16];
  #pragma unroll
  for (int p = 0; p < 2; p++) {
    uint4 u = *(const uint4*)&row[(size_t)(p * 256 + tid) * 8];
    unsigned int uu[4] = {u.x, u.y, u.z, u.w};
    #pragma unroll
    for (int j = 0; j < 4; j++) {
      v[p * 8 + j * 2 + 0] = b2f((u16)(uu[j] & 0xffff));
      v[p * 8 + j * 2 + 1] = b2f((u16)(uu[j] >> 16));
    }
  }
  float m = -1e30f;
  #pragma unroll
  for (int i = 0; i < 16; i++) m = fmaxf(m, v[i]);
  #pragma unroll
  for (int o = 32; o; o >>= 1) m = fmaxf(m, __shfl_xor(m, o));
  __shared__ float sm[4], ss[4];
  int w = tid >> 6;
  if ((tid & 63) == 0) sm[w] = m;
  __syncthreads();
  m = fmaxf(fmaxf(sm[0], sm[1]), fmaxf(sm[2], sm[3]));
  float s = 0.f;
  #pragma unroll
  for (int i = 0; i < 16; i++) s += __expf(v[i] - m);
  #pragma unroll
  for (int o = 32; o; o >>= 1) s += __shfl_xor(s, o);
  if ((tid & 63) == 0) ss[w] = s;
  __syncthreads();
  if (tid == 0) {
    rmax[r] = m;
    rinv[r] = 1.f / (ss[0] + ss[1] + ss[2] + ss[3]);
  }
}

// ---------------- K2b: ctx[d][e] += sum_n softmax(k)[d][n] * v[e][n] ----------------
#define CCH 128
__global__ __launch_bounds__(256) void k_context(const u16* __restrict__ qkvb,
    const float* __restrict__ rmax, const float* __restrict__ rinv,
    float* __restrict__ ctx) {
  int bh = blockIdx.y;
  int b = bh >> 2, hd = bh & 3;
  int c0 = blockIdx.x * 4;
  const u16* kb = qkvb + (size_t)b * OC3_ * N_ + (size_t)(HID_ + hd * DH_) * N_;
  const u16* vb = qkvb + (size_t)b * OC3_ * N_ + (size_t)(2 * HID_ + hd * DH_) * N_;
  __shared__ float ks[32][129];
  __shared__ float vs[128][40];
  int tid = threadIdx.x;
  int n8 = (tid & 15) * 8;
  int dd = tid >> 3, e0 = (tid & 7) * 4;
  f32x4 acc = {};
  for (int cc = 0; cc < 4; cc++) {
    int nb = (c0 + cc) * CCH;
    if (cc) __syncthreads();
    #pragma unroll
    for (int h = 0; h < 2; h++) {
      int d = (tid >> 4) + h * 16;
      float rm = rmax[bh * 32 + d], ri = rinv[bh * 32 + d];
      uint4 ku = *(const uint4*)&kb[(size_t)d * N_ + nb + n8];
      uint4 vu = *(const uint4*)&vb[(size_t)d * N_ + nb + n8];
      unsigned int kk[4] = {ku.x, ku.y, ku.z, ku.w};
      unsigned int vv[4] = {vu.x, vu.y, vu.z, vu.w};
      #pragma unroll
      for (int j = 0; j < 4; j++) {
        ks[d][n8 + j * 2 + 0] = __expf(b2f((u16)(kk[j] & 0xffff)) - rm) * ri;
        ks[d][n8 + j * 2 + 1] = __expf(b2f((u16)(kk[j] >> 16)) - rm) * ri;
        vs[n8 + j * 2 + 0][d] = b2f((u16)(vv[j] & 0xffff));
        vs[n8 + j * 2 + 1][d] = b2f((u16)(vv[j] >> 16));
      }
    }
    __syncthreads();
    for (int n = 0; n < CCH; n++) {
      float kd = ks[dd][n];
      f32x4 v4 = *(const f32x4*)&vs[n][e0];
      acc += kd * v4;
    }
  }
  float* cp = &ctx[(size_t)(bh * 32 + dd) * 32 + e0];
  atomicAdd(cp + 0, acc[0]); atomicAdd(cp + 1, acc[1]);
  atomicAdd(cp + 2, acc[2]); atomicAdd(cp + 3, acc[3]);
}

// ---------------- K3: q-softmax + hid = ctx^T . q -> hidt[b][n][e] bf16 ----------------
__global__ __launch_bounds__(256) void k_attnout(const u16* __restrict__ qkvb,
    const float* __restrict__ ctx, u16* __restrict__ hidt) {
  int tile = blockIdx.x, bh = blockIdx.y;
  int b = bh >> 2, hd = bh & 3;
  const u16* qbase = qkvb + (size_t)b * OC3_ * N_ + (size_t)(hd * DH_) * N_;
  __shared__ float cs[32][40];
  __shared__ unsigned int hs[256][16];  // 256 n x 32 bf16 (packed pairs)
  int tid = threadIdx.x;
  for (int idx = tid; idx < 1024; idx += 256) {
    int d = idx >> 5, e = idx & 31;
    cs[d][e] = ctx[(size_t)bh * 1024 + idx];
  }
  __syncthreads();
  int n = tile * 256 + tid;
  float q[32];
  float m = -1e30f;
  #pragma unroll
  for (int d = 0; d < 32; d++) { q[d] = b2f(qbase[(size_t)d * N_ + n]); m = fmaxf(m, q[d]); }
  float s = 0.f;
  #pragma unroll
  for (int d = 0; d < 32; d++) { q[d] = __expf(q[d] - m); s += q[d]; }
  float inv = 0.17677669529663687f / s;  // 1/sqrt(32)
  #pragma unroll
  for (int d = 0; d < 32; d++) q[d] *= inv;
  #pragma unroll
  for (int e0 = 0; e0 < 32; e0 += 4) {
    f32x4 a = {};
    #pragma unroll
    for (int d = 0; d < 32; d++) {
      f32x4 c4 = *(const f32x4*)&cs[d][e0];
      a += q[d] * c4;
    }
    hs[tid][e0 / 2 + 0] = (unsigned int)f2b(a[0]) | ((unsigned int)f2b(a[1]) << 16);
    hs[tid][e0 / 2 + 1] = (unsigned int)f2b(a[2]) | ((unsigned int)f2b(a[3]) << 16);
  }
  __syncthreads();
  #pragma unroll
  for (int it = 0; it < 8; it++) {
    int q2 = it * 256 + tid;          // uint2 chunk: 8 chunks per n-row
    int nl = q2 >> 3, c2 = q2 & 7;
    uint2 v = *(const uint2*)&hs[nl][c2 * 2];
    *(uint2*)&hidt[((size_t)b * N_ + tile * 256 + nl) * HID_ + hd * 32 + c2 * 4] = v;
  }
}

// ---------------- K5: finalize mean/rstd ----------------
__global__ void k_finalize(float* __restrict__ bsum) {
  int b = threadIdx.x;
  if (b < B_) {
    float s1 = bsum[2 * b], s2 = bsum[2 * b + 1];
    float mean = s1 * (1.f / LNM_);
    float var = s2 * (1.f / LNM_) - mean * mean;
    bsum[2 * b] = mean;
    bsum[2 * b + 1] = rsqrtf(var + 1e-5f);
  }
}

// ---------------- K6: normalize + affine in-place ----------------
__global__ __launch_bounds__(256) void k_norm(float* __restrict__ out,
    const float* __restrict__ bsum, const float* __restrict__ gnw,
    const float* __restrict__ gnb) {
  size_t v = (size_t)blockIdx.x * 256 + threadIdx.x;
  int c = (int)((v >> 10) & 255);
  int b = (int)(v >> 18);
  float mean = bsum[2 * b], rstd = bsum[2 * b + 1];
  float w = gnw[c] * rstd;
  float sh = gnb[c] - mean * w;
  float4 x = ((const float4*)out)[v];
  x.x = x.x * w + sh; x.y = x.y * w + sh;
  x.z = x.z * w + sh; x.w = x.w * w + sh;
  ((float4*)out)[v] = x;
}

extern "C" void kernel_launch(void* const* d_in, const int* in_sizes, int n_in,
                              void* d_out, int out_size, void* d_ws, size_t ws_size,
                              hipStream_t stream) {
  const float* x     = (const float*)d_in[0];
  const float* w_qkv = (const float*)d_in[1];
  const float* w_out = (const float*)d_in[2];
  const float* b_out = (const float*)d_in[3];
  const float* gn_w  = (const float*)d_in[4];
  const float* gn_b  = (const float*)d_in[5];
  float* out = (float*)d_out;

  u16* qkvb = (u16*)d_ws;                              // 96 MiB
  u16* xt   = qkvb + (size_t)B_ * OC3_ * N_;           // 64 MiB
  u16* hidt = xt;                                       // alias: xt dead after GEMM1
  float* ctx  = (float*)(xt + (size_t)B_ * N_ * C_);   // 512 KiB
  float* bsum = ctx + 131072;                          // 64
  float* rmax = bsum + 64;                             // 4096
  float* rinv = rmax + 4096;                           // 4096
  u16* wqb = (u16*)(rinv + 4096);                      // 192 KiB
  u16* wob = wqb + OC3_ * C_;                          // 64 KiB

  k_cast_w<<<384, 256, 0, stream>>>(w_qkv, w_out, wqb, wob);
  k_transpose<<<dim3(64, 4, 32), 256, 0, stream>>>(x, xt);
  k_zero<<<64, 256, 0, stream>>>(ctx, 131072 + 64);
  k_gemm_mfma<256, true><<<dim3(32, 3, 32), 256, 0, stream>>>(wqb, xt, qkvb, nullptr, nullptr, OC3_);
  k_kstats<<<4096, 256, 0, stream>>>(qkvb, rmax, rinv);
  k_context<<<dim3(8, 128), 256, 0, stream>>>(qkvb, rmax, rinv, ctx);
  k_attnout<<<dim3(16, 128), 256, 0, stream>>>(qkvb, ctx, hidt);
  k_gemm_mfma<128, false><<<dim3(32, 2, 32), 256, 0, stream>>>(wob, hidt, out, b_out, bsum, C_);
  k_finalize<<<1, 64, 0, stream>>>(bsum);
  k_norm<<<32768, 256, 0, stream>>>(out, bsum, gn_w, gn_b);
}